// Round 4
// baseline (268.082 us; speedup 1.0000x reference)
//
#include <hip/hip_runtime.h>

#define NIN   1152
#define NOUT  10
#define CMAX  5    // waves 0-1 own 5 capsules, waves 2-3 own 4 (128*5+128*4=1152)

// One block per (batch, out_capsule), 256 threads, XCD-swizzled (neutral, kept
// for locality). Thread t owns WHOLE capsules i = t + 256k, k < c (c=5 for
// t<128 else 4; wave-uniform). b, w, agreement are register-resident (no LDS).
// s-reduction: 16-float wave fold-reduce (payload halves per xor step) + tiny
// LDS cross-wave combine. 4 barriers/iter (was 8), ~40 DS ops/thread-iter
// (was ~114).
__global__ __launch_bounds__(256)
void routing_kernel(const float* __restrict__ u_hat, float* __restrict__ out) {
    __shared__ float l2s[4][16];              // per-wave folded S
    __shared__ __align__(16) float vsh[16];   // s (softmax-normalized)
    __shared__ float scal[8];                 // per-wave max / sum

    const int t    = threadIdx.x;
    const int wave = t >> 6;
    const int lane = t & 63;

    // XCD-aware decode: 2560 blocks = 8 XCDs x 32 bb x 10 oo (bijective)
    const int x   = blockIdx.x;
    const int xcd = x & 7;
    const int j   = x >> 3;
    const int oo  = j % NOUT;
    const int bb  = xcd * 32 + j / NOUT;

    const int c = (t < 128) ? 5 : 4;          // wave-uniform capsule count

    // u_hat flat: ((bb*NIN + i)*NOUT + oo)*16 + d ; row stride = 160 floats
    const float* base = u_hat + ((size_t)bb * NIN + t) * (NOUT * 16) + oo * 16;

    float4 u[CMAX][4];
#pragma unroll
    for (int k = 0; k < CMAX; ++k) {
        if (k < c) {
            const float* rp = base + (size_t)k * 256 * (NOUT * 16);
            u[k][0] = *reinterpret_cast<const float4*>(rp);
            u[k][1] = *reinterpret_cast<const float4*>(rp + 4);
            u[k][2] = *reinterpret_cast<const float4*>(rp + 8);
            u[k][3] = *reinterpret_cast<const float4*>(rp + 12);
        }
    }

    float b[CMAX] = {0.f, 0.f, 0.f, 0.f, 0.f};

    for (int r = 0; r < 3; ++r) {
        // ---- block max of b (register-resident logits) ----
        float m = b[0];
#pragma unroll
        for (int k = 1; k < CMAX; ++k) if (k < c) m = fmaxf(m, b[k]);
        for (int off = 32; off >= 1; off >>= 1) m = fmaxf(m, __shfl_down(m, off));
        if (lane == 0) scal[wave] = m;
        __syncthreads();
        const float M = fmaxf(fmaxf(scal[0], scal[1]), fmaxf(scal[2], scal[3]));

        // ---- e = exp(b - M), Z ----
        float e[CMAX];
        float z = 0.f;
#pragma unroll
        for (int k = 0; k < CMAX; ++k) {
            if (k < c) { e[k] = __expf(b[k] - M); z += e[k]; }
        }
        for (int off = 32; off >= 1; off >>= 1) z += __shfl_down(z, off);
        if (lane == 0) scal[4 + wave] = z;
        __syncthreads();
        const float invZ = 1.0f / (scal[4] + scal[5] + scal[6] + scal[7]);

        // ---- per-thread partial S[16] = sum_k e_k * u_k ----
        float A[16];
#pragma unroll
        for (int d = 0; d < 16; ++d) A[d] = 0.f;
#pragma unroll
        for (int k = 0; k < CMAX; ++k) {
            if (k < c) {
                const float w = e[k];
                A[ 0] += w * u[k][0].x; A[ 1] += w * u[k][0].y;
                A[ 2] += w * u[k][0].z; A[ 3] += w * u[k][0].w;
                A[ 4] += w * u[k][1].x; A[ 5] += w * u[k][1].y;
                A[ 6] += w * u[k][1].z; A[ 7] += w * u[k][1].w;
                A[ 8] += w * u[k][2].x; A[ 9] += w * u[k][2].y;
                A[10] += w * u[k][2].z; A[11] += w * u[k][2].w;
                A[12] += w * u[k][3].x; A[13] += w * u[k][3].y;
                A[14] += w * u[k][3].z; A[15] += w * u[k][3].w;
            }
        }

        // ---- wave fold-reduce of A[16]: payload halves each xor step ----
        {   // xor 32: 16 -> 8  (hi lanes end owning d in [8,16))
            const bool hi = (lane & 32) != 0;
#pragma unroll
            for (int i = 0; i < 8; ++i) {
                const float snd = hi ? A[i] : A[i + 8];
                const float rcv = __shfl_xor(snd, 32);
                A[i] = (hi ? A[i + 8] : A[i]) + rcv;
            }
        }
        {   // xor 16: 8 -> 4
            const bool hi = (lane & 16) != 0;
#pragma unroll
            for (int i = 0; i < 4; ++i) {
                const float snd = hi ? A[i] : A[i + 4];
                const float rcv = __shfl_xor(snd, 16);
                A[i] = (hi ? A[i + 4] : A[i]) + rcv;
            }
        }
        {   // xor 8: 4 -> 2
            const bool hi = (lane & 8) != 0;
#pragma unroll
            for (int i = 0; i < 2; ++i) {
                const float snd = hi ? A[i] : A[i + 2];
                const float rcv = __shfl_xor(snd, 8);
                A[i] = (hi ? A[i + 2] : A[i]) + rcv;
            }
        }
        {   // xor 4: 2 -> 1
            const bool hi = (lane & 4) != 0;
            const float snd = hi ? A[1] : A[1];
            // NOTE: send the inactive element, keep the active one:
            const float snd2 = hi ? A[0] : A[1];
            (void)snd;
            const float rcv = __shfl_xor(snd2, 4);
            A[0] = (hi ? A[1] : A[0]) + rcv;
        }
        // quad sum (payload 1): lanes 4d..4d+3 all hold wave-sum for d = lane>>2
        A[0] += __shfl_xor(A[0], 2);
        A[0] += __shfl_xor(A[0], 1);
        if ((lane & 3) == 0) l2s[wave][lane >> 2] = A[0];
        __syncthreads();

        if (t < 16) {
            vsh[t] = (l2s[0][t] + l2s[1][t] + l2s[2][t] + l2s[3][t]) * invZ;
        }
        __syncthreads();

        // ---- squash: broadcast-read s, redundant scalar math per thread ----
        const float4 s0 = *reinterpret_cast<const float4*>(&vsh[0]);
        const float4 s1 = *reinterpret_cast<const float4*>(&vsh[4]);
        const float4 s2 = *reinterpret_cast<const float4*>(&vsh[8]);
        const float4 s3 = *reinterpret_cast<const float4*>(&vsh[12]);
        const float sqr =
            s0.x*s0.x + s0.y*s0.y + s0.z*s0.z + s0.w*s0.w +
            s1.x*s1.x + s1.y*s1.y + s1.z*s1.z + s1.w*s1.w +
            s2.x*s2.x + s2.y*s2.y + s2.z*s2.z + s2.w*s2.w +
            s3.x*s3.x + s3.y*s3.y + s3.z*s3.z + s3.w*s3.w;
        const float scale = sqr / ((1.0f + sqr) * sqrtf(sqr + 1e-7f));

        if (r == 2) {
            if (t < 16) out[(size_t)(bb * NOUT + oo) * 16 + t] = vsh[t] * scale;
            break;
        }

        // ---- agreement: thread-local dot, b update in registers (zero DS) ----
#pragma unroll
        for (int k = 0; k < CMAX; ++k) {
            if (k < c) {
                const float dot =
                    u[k][0].x*s0.x + u[k][0].y*s0.y + u[k][0].z*s0.z + u[k][0].w*s0.w +
                    u[k][1].x*s1.x + u[k][1].y*s1.y + u[k][1].z*s1.z + u[k][1].w*s1.w +
                    u[k][2].x*s2.x + u[k][2].y*s2.y + u[k][2].z*s2.z + u[k][2].w*s2.w +
                    u[k][3].x*s3.x + u[k][3].y*s3.y + u[k][3].z*s3.z + u[k][3].w*s3.w;
                b[k] += dot * scale;   // v = s*scale, folded into the dot
            }
        }
    }
}

extern "C" void kernel_launch(void* const* d_in, const int* in_sizes, int n_in,
                              void* d_out, int out_size, void* d_ws, size_t ws_size,
                              hipStream_t stream) {
    const float* u_hat = (const float*)d_in[0];
    float* out = (float*)d_out;
    routing_kernel<<<dim3(256 * NOUT), dim3(256), 0, stream>>>(u_hat, out);
}

// Round 5
// 262.913 us; speedup vs baseline: 1.0197x; 1.0197x over previous
//
#include <hip/hip_runtime.h>

#define NIN   1152
#define NOUT  10
#define KPT   18   // rows per thread

// R5: oo-pair blocks for 128-B-granular dense loads.
// Block = (bb, p), p in [0,5): covers oo in {2p, 2p+1}. 512 threads, 8 waves.
// Thread t: q = t&3 (d-quad), o = (t>>2)&1 (which oo), g = t>>3 (row group);
// owns rows i = g + 64k, k<18, as float4 u[k] = u_hat[bb, i, 2p+o, 4q..4q+4).
// Wave-load geometry: lanes 0..7 read 8 consecutive float4s = one aligned
// 128-B line; one wave-load = 8 full lines (R1: 16 half-lines shared with a
// neighbor block). Compute = faithful R1 structure per oo (zero-init b, full
// softmax each iter, += agreement).
__global__ __launch_bounds__(512, 4)
void routing_kernel(const float* __restrict__ u_hat, float* __restrict__ out) {
    __shared__ float bsh[2][NIN];                 // logits per oo
    __shared__ float wsh[2][NIN];                 // exp(b - M) per oo
    __shared__ __align__(16) float red[8][2][16]; // per-wave s partials
    __shared__ __align__(16) float vsh[2][16];    // s (then scaled at output)
    __shared__ float msc[8][2];                   // per-wave max partials
    __shared__ float zsc[8][2];                   // per-wave sum partials

    const int t    = threadIdx.x;
    const int q    = t & 3;
    const int o    = (t >> 2) & 1;
    const int g    = t >> 3;        // 0..63
    const int wave = t >> 6;        // 0..7
    const int lane = t & 63;

    const int bb = blockIdx.x / 5;
    const int p  = blockIdx.x % 5;

    // float col offset within a 160-float row: p*32 + (q + 4o)*4
    const float* base = u_hat + (size_t)bb * (NIN * NOUT * 16) + p * 32 + (t & 7) * 4;

    float4 u[KPT];
#pragma unroll
    for (int k = 0; k < KPT; ++k) {
        u[k] = *reinterpret_cast<const float4*>(base + (size_t)(g + 64 * k) * 160);
    }

    for (int i = t; i < 2 * NIN; i += 512) (&bsh[0][0])[i] = 0.0f;
    __syncthreads();

    const int tid_o = q + (g << 2);   // [0,256) within this thread's oo-partition

    for (int r = 0; r < 3; ++r) {
        // ---- per-oo max over i ----
        float m = -3.4e38f;
        for (int i = tid_o; i < NIN; i += 256) m = fmaxf(m, bsh[o][i]);
        // reduce over lanes sharing o: strides 32,16,8 keep (q,o); xor 1,2 cross q only
        m = fmaxf(m, __shfl_down(m, 32));
        m = fmaxf(m, __shfl_down(m, 16));
        m = fmaxf(m, __shfl_down(m, 8));
        m = fmaxf(m, __shfl_xor(m, 1));
        m = fmaxf(m, __shfl_xor(m, 2));
        if (lane == 0 || lane == 4) msc[wave][(lane >> 2) & 1] = m;
        __syncthreads();
        float M = msc[0][o];
#pragma unroll
        for (int w = 1; w < 8; ++w) M = fmaxf(M, msc[w][o]);

        // ---- e = exp(b - M), Z ----
        float z = 0.0f;
        for (int i = tid_o; i < NIN; i += 256) {
            const float w = __expf(bsh[o][i] - M);
            wsh[o][i] = w;
            z += w;
        }
        z += __shfl_down(z, 32);
        z += __shfl_down(z, 16);
        z += __shfl_down(z, 8);
        z += __shfl_xor(z, 1);
        z += __shfl_xor(z, 2);
        if (lane == 0 || lane == 4) zsc[wave][(lane >> 2) & 1] = z;
        __syncthreads();
        float Z = 0.0f;
#pragma unroll
        for (int w = 0; w < 8; ++w) Z += zsc[w][o];
        const float invZ = 1.0f / Z;

        // ---- s partial: thread sums its 18 rows (d-quad q of its oo) ----
        float sx = 0.f, sy = 0.f, sz = 0.f, sw = 0.f;
#pragma unroll
        for (int k = 0; k < KPT; ++k) {
            const float w = wsh[o][g + 64 * k];
            sx += w * u[k].x; sy += w * u[k].y; sz += w * u[k].z; sw += w * u[k].w;
        }
        // reduce over g within the wave: strides 32,16,8 keep (q,o)
        for (int off = 32; off >= 8; off >>= 1) {
            sx += __shfl_down(sx, off);
            sy += __shfl_down(sy, off);
            sz += __shfl_down(sz, off);
            sw += __shfl_down(sw, off);
        }
        if (lane < 8) {
            float4 sv; sv.x = sx; sv.y = sy; sv.z = sz; sv.w = sw;
            *reinterpret_cast<float4*>(&red[wave][(lane >> 2) & 1][(lane & 3) * 4]) = sv;
        }
        __syncthreads();
        if (t < 32) {
            const int oi = t >> 4, d = t & 15;
            float acc = 0.0f;
#pragma unroll
            for (int w = 0; w < 8; ++w) acc += red[w][oi][d];
            float Zo = 0.0f;
#pragma unroll
            for (int w = 0; w < 8; ++w) Zo += zsc[w][oi];
            vsh[oi][d] = acc / Zo;
        }
        __syncthreads();

        // ---- squash scales for both oo (redundant broadcast reads) ----
        float sq0 = 0.f, sq1 = 0.f;
#pragma unroll
        for (int d = 0; d < 16; ++d) {
            const float a0 = vsh[0][d], a1 = vsh[1][d];
            sq0 += a0 * a0; sq1 += a1 * a1;
        }
        const float sc0 = sq0 / ((1.0f + sq0) * sqrtf(sq0 + 1e-7f));
        const float sc1 = sq1 / ((1.0f + sq1) * sqrtf(sq1 + 1e-7f));

        if (r == 2) {
            if (t < 32) {
                const int oi = t >> 4, d = t & 15;
                out[((size_t)bb * NOUT + 2 * p + oi) * 16 + d] =
                    vsh[oi][d] * (oi ? sc1 : sc0);
            }
            break;
        }

        // ---- agreement: a_i = (u_i . s) * scale ; b_i += a_i ----
        const float scale = o ? sc1 : sc0;
        const float4 vq = *reinterpret_cast<const float4*>(&vsh[o][q * 4]);
#pragma unroll
        for (int k = 0; k < KPT; ++k) {
            float a = u[k].x * vq.x + u[k].y * vq.y + u[k].z * vq.z + u[k].w * vq.w;
            a += __shfl_xor(a, 1);
            a += __shfl_xor(a, 2);
            if (q == 0) bsh[o][g + 64 * k] += a * scale;
        }
        __syncthreads();
    }
}

extern "C" void kernel_launch(void* const* d_in, const int* in_sizes, int n_in,
                              void* d_out, int out_size, void* d_ws, size_t ws_size,
                              hipStream_t stream) {
    const float* u_hat = (const float*)d_in[0];
    float* out = (float*)d_out;
    routing_kernel<<<dim3(256 * 5), dim3(512), 0, stream>>>(u_hat, out);
}